// Round 1
// 96.548 us; speedup vs baseline: 1.0203x; 1.0203x over previous
//
#include <hip/hip_runtime.h>
#include <math.h>

namespace {
constexpr int kNpts = 32 * 32 * 32;   // 32768 frequency points
constexpr int kHalf = kNpts / 2;      // 16384 conj-unique points (p and 32767-p conjugate)
constexpr int kNF = 1024;             // faces
constexpr int kWaves = 16;            // waves per fourier block (1024 threads)
constexpr int kFaceHalves = 2;        // face-dim split across blocks -> 2x occupancy
constexpr int kFPG = kNF / (kWaves * kFaceHalves);  // 32 faces per wave-group
constexpr int kRec = 12;              // elements per face record (both f64 and f32 tables)
// d_ws layout (offsets in doubles):
//   [0..2)    per-block f32 area partial sums (face_prep grid = 4 blocks; 4 floats)
//   [8]       unsigned slow-pair counter (zeroed by face_prep each launch)
//   [64..)    f64 face records: 12*1024 doubles (slow path, exact ref replica)
//   then      f32 face records: 12*1024 floats  (fast path)
//   then      partial grids: kFaceHalves * kHalf float2
//   then      slow-pair list: uint32 entries ((face<<14)|p)
constexpr int kRec64Off = 64;
constexpr int kRec32OffD = kRec64Off + kRec * kNF;          // 12352 doubles
constexpr int kGridOffD = kRec32OffD + (kRec * kNF) / 2;    // 18496 doubles
constexpr int kSlowCntD = 8;                                // counter double-offset
constexpr int kSlowListD = kGridOffD + kFaceHalves * kHalf; // 51264 doubles
}

__device__ __forceinline__ float fract32(float x) {
#if __has_builtin(__builtin_amdgcn_fractf)
    return __builtin_amdgcn_fractf(x);
#else
    return x - floorf(x);
#endif
}

// ---- Kernel A: per-face prep, 4 blocks x 256 threads; dual f64/f32 records ----
// f64 kept ONLY for slow-path vertex coords (phase cancellation); area/meshar
// are linear scale factors -> f32 chain (halves the latency-bound dep chain).
__global__ __launch_bounds__(256) void face_prep(
        const float* __restrict__ verts, const float* __restrict__ box,
        const int* __restrict__ faces, double* __restrict__ ws) {
    __shared__ float wsum[4];
    const int f = blockIdx.x * 256 + threadIdx.x;
    if (blockIdx.x == 0 && threadIdx.x == 0)
        *(unsigned*)(ws + kSlowCntD) = 0u;   // ws is re-poisoned each iter: must init
    const double lo0 = (double)box[0], lo1 = (double)box[2], lo2 = (double)box[4];
    const int ia = faces[3 * f + 0], ib = faces[3 * f + 1], ic = faces[3 * f + 2];
    const double ax = (double)verts[3 * ia + 0] - lo0, ay = (double)verts[3 * ia + 1] - lo1, az = (double)verts[3 * ia + 2] - lo2;
    const double bx = (double)verts[3 * ib + 0] - lo0, by = (double)verts[3 * ib + 1] - lo1, bz = (double)verts[3 * ib + 2] - lo2;
    const double cx = (double)verts[3 * ic + 0] - lo0, cy = (double)verts[3 * ic + 1] - lo1, cz = (double)verts[3 * ic + 2] - lo2;
    const float axf = (float)ax, ayf = (float)ay, azf = (float)az;
    const float bxf = (float)bx, byf = (float)by, bzf = (float)bz;
    const float cxf = (float)cx, cyf = (float)cy, czf = (float)cz;
    const float e1x = bxf - axf, e1y = byf - ayf, e1z = bzf - azf;
    const float e2x = cxf - axf, e2y = cyf - ayf, e2z = czf - azf;
    const float crx = e1y * e2z - e1z * e2y;
    const float cry = e1z * e2x - e1x * e2z;
    const float crz = e1x * e2y - e1y * e2x;
    const float area = 0.5f * sqrtf(crx * crx + cry * cry + crz * crz);
    float a = area;
    a += __shfl_down(a, 32, 64);
    a += __shfl_down(a, 16, 64);
    a += __shfl_down(a, 8, 64);
    a += __shfl_down(a, 4, 64);
    a += __shfl_down(a, 2, 64);
    a += __shfl_down(a, 1, 64);
    if ((threadIdx.x & 63) == 0) wsum[threadIdx.x >> 6] = a;
    __syncthreads();
    if (threadIdx.x == 0)
        ((float*)ws)[blockIdx.x] = ((wsum[0] + wsum[1]) + wsum[2]) + wsum[3];
    double* r = ws + kRec64Off + (size_t)kRec * f;
    r[0] = ax; r[1] = ay; r[2] = az;
    r[3] = bx; r[4] = by; r[5] = bz;
    r[6] = cx; r[7] = cy; r[8] = cz;
    r[9] = (double)area;
    r[10] = 0.0; r[11] = 0.0;
    float* r32 = (float*)(ws + kRec32OffD) + (size_t)kRec * f;
    r32[0] = axf; r32[1] = ayf; r32[2] = azf;
    r32[3] = bxf; r32[4] = byf; r32[5] = bzf;
    r32[6] = cxf; r32[7] = cyf; r32[8] = czf;
    r32[9] = area * 0.025330296f;  // area/(4*pi^2): rev^2 -> rad^2 denom scale
    r32[10] = 0.0f; r32[11] = 0.0f;
}

// exact f64 replica of the reference's pair case value
__device__ __forceinline__ void pair_case_f64(double x1, double x2, double x3,
                                              double& vr, double& vi) {
    const double m = (x1 + x2) * 0.5;
    const double d = m - x3;
    double sm, cm, s3, c3;
    sincos(m, &sm, &cm);
    sincos(x3, &s3, &c3);
    vr = (sm + (cm - c3) / d) / d;
    vi = (cm + (s3 - sm) / d) / d;
}

// ---- Kernel B: main Fourier sum, PURE f32. Rare near-degenerate pairs are
// appended to a device-side list and contribute 0 here; fourier_fix replays
// them in exact f64 afterwards. Keeps f64/ocml-sincos out of this function so
// __launch_bounds__(1024,8)'s 64-VGPR cap is met without spills. ----
__global__ __launch_bounds__(kWaves * 64, 8) void fourier_main(
        double* __restrict__ ws, const float* __restrict__ xi0,
        const float* __restrict__ xi1, const float* __restrict__ xi2, int cap) {
    const float INV_TWO_PI_F = 0.15915494f;
    // fast/slow gate on min |product of two phase-diffs| in rev^2 (= 1e-3 rad^2)
    const float TAUP_REV2 = 2.5330296e-5f;

    const int t = threadIdx.x;
    const int l = t & 63;                 // lane -> point within group
    const int w = t >> 6;                 // wave -> face subgroup
    const int pb = blockIdx.x & 255;      // point group
    const int fh = blockIdx.x >> 8;       // face half
    const int p = pb * 64 + l;            // p in [0, kHalf)
    const int i2 = p & 31, i1 = (p >> 5) & 31, i0 = p >> 10;
    const float x0 = xi0[i0], x1 = xi1[i1], x2 = xi2[i2];
    const float xxr = x0 * INV_TWO_PI_F;
    const float xyr = x1 * INV_TWO_PI_F;
    const float xzr = x2 * INV_TWO_PI_F;

    float re = 0.0f, im = 0.0f;
    const int grp = __builtin_amdgcn_readfirstlane(fh * kWaves + w);
    const float* fp32 = (const float*)(ws + kRec32OffD) + (size_t)grp * kFPG * kRec;
    unsigned* cnt = (unsigned*)(ws + kSlowCntD);
    unsigned* list = (unsigned*)(ws + kSlowListD);

#pragma unroll 4
    for (int i = 0; i < kFPG; ++i) {
        const float* r = fp32 + i * kRec;
        // phases in revolutions, all f32 (conditioning: F has O(1) derivatives,
        // so f32 phase noise -> ~6e-5*wgt output error; 1/d blowup is internal
        // cancellation and stays consistent as long as diffs come from phases)
        const float ra = fmaf(xzr, r[2], fmaf(xyr, r[1], xxr * r[0]));
        const float rb = fmaf(xzr, r[5], fmaf(xyr, r[4], xxr * r[3]));
        const float rc = fmaf(xzr, r[8], fmaf(xyr, r[7], xxr * r[6]));
        const float fdab = rb - ra, fdbc = rc - rb, fdca = ra - rc;
        const float d1 = fdab * fdca;   // rev^2
        const float d2 = fdbc * fdab;
        const float d3 = fdca * fdbc;
        const float mn = fminf(fminf(fabsf(d1), fabsf(d2)), fabsf(d3));

        if (mn > TAUP_REV2) {
            // fast path: all f32 — v_fract -> hw v_sin/v_cos (rev input), 1 rcp.
            // area/(4pi^2) scale folded into the reciprocal (saves 2 outer fma).
            const float R3w = __builtin_amdgcn_rcpf(d1 * fdbc) * r[9];
            const float r1 = fdbc * R3w, r2 = fdca * R3w, r3 = fdab * R3w;
            const float fa = fract32(ra);
            const float fb = fract32(rb);
            const float fc = fract32(rc);
            const float sa = __builtin_amdgcn_sinf(fa), ca = __builtin_amdgcn_cosf(fa);
            const float sb = __builtin_amdgcn_sinf(fb), cb = __builtin_amdgcn_cosf(fb);
            const float sc = __builtin_amdgcn_sinf(fc), cc = __builtin_amdgcn_cosf(fc);
            re = fmaf(cc, r3, fmaf(cb, r2, fmaf(ca, r1, re)));
            im = fmaf(-sc, r3, fmaf(-sb, r2, fmaf(-sa, r1, im)));
        } else {
            // rare: defer to f64 fixup kernel; contribute 0 here
            const unsigned idx = atomicAdd(cnt, 1u);
            if ((int)idx < cap)
                list[idx] = ((unsigned)(grp * kFPG + i) << 14) | (unsigned)p;
        }
    }

    // reduce kWaves partials per point; write this face-half's partial grid
    __shared__ float pr[kWaves][64];
    __shared__ float pi[kWaves][64];
    pr[w][l] = re;
    pi[w][l] = im;
    __syncthreads();
    if (w == 0) {
        float R = pr[0][l], I = pi[0][l];
#pragma unroll
        for (int g = 1; g < kWaves; ++g) { R += pr[g][l]; I += pi[g][l]; }
        float2* pg = (float2*)(ws + kGridOffD);
        pg[(size_t)fh * kHalf + p] = make_float2(R, I);
    }
}

// ---- Kernel B2: replay near-degenerate pairs in exact f64 (reference region
// logic, bit-identical to the old inline slow path); atomic-add into half-0
// partial grid. Expected list length O(10^3): negligible runtime. ----
__global__ __launch_bounds__(256) void fourier_fix(
        double* __restrict__ ws, const float* __restrict__ xi0,
        const float* __restrict__ xi1, const float* __restrict__ xi2, int cap) {
    const double SEPS = __builtin_sqrt(1.19209e-07);  // matches float(np.sqrt(EPS))
    const double TWO_PI = 6.283185307179586;
    const double INV_TWO_PI = 0.15915494309189535;
    unsigned n = *(const unsigned*)(ws + kSlowCntD);
    if (n > (unsigned)cap) n = (unsigned)cap;
    const unsigned* list = (const unsigned*)(ws + kSlowListD);
    float* pg = (float*)(ws + kGridOffD);
    for (unsigned idx = blockIdx.x * 256 + threadIdx.x; idx < n;
         idx += gridDim.x * 256) {
        const unsigned e = list[idx];
        const int p = (int)(e & 16383u);
        const int f = (int)(e >> 14);
        const int i2 = p & 31, i1 = (p >> 5) & 31, i0 = p >> 10;
        const double xxd = (double)xi0[i0] * INV_TWO_PI;
        const double xyd = (double)xi1[i1] * INV_TWO_PI;
        const double xzd = (double)xi2[i2] * INV_TWO_PI;
        const double* r64 = ws + kRec64Off + (size_t)kRec * f;
        const double rad = fma(xzd, r64[2], fma(xyd, r64[1], xxd * r64[0]));
        const double rbd = fma(xzd, r64[5], fma(xyd, r64[4], xxd * r64[3]));
        const double rcd = fma(xzd, r64[8], fma(xyd, r64[7], xxd * r64[6]));
        const double area = r64[9];
        const double xa = rad * TWO_PI, xb = rbd * TWO_PI, xc = rcd * TWO_PI;
        const double dAB = xb - xa, dBC = xc - xb, dCA = xa - xc;
        const double aab = fabs(dAB), abc = fabs(dBC), aca = fabs(dCA);
        const bool s2 = aab < SEPS, s3 = abc < SEPS, s4 = aca < SEPS;
        const bool c2 = aab <= SEPS, c3 = abc <= SEPS, c4 = aca <= SEPS;
        const bool R1 = (s2 && s3) || (s3 && s4) || (s4 && s2);
        const bool R2 = c2 && !R1;
        const bool R3b = c3 && !R2 && !R1;
        const bool R4 = c4 && !R3b && !R2 && !R1;
        double vr, vi;
        if (R1) {
            const double m = ((xa + xb) + xc) / 3.0;
            double sm, cm;
            sincos(m, &sm, &cm);
            vr = cm / 2.0;
            vi = -sm / 2.0;
        } else if (R2) {
            pair_case_f64(xa, xb, xc, vr, vi);
        } else if (R3b) {
            pair_case_f64(xb, xc, xa, vr, vi);
        } else if (R4) {
            pair_case_f64(xc, xa, xb, vr, vi);
        } else {
            double sa, ca, sb, cb, sc, cc;
            sincos(xa, &sa, &ca);
            sincos(xb, &sb, &cb);
            sincos(xc, &sc, &cc);
            const double da = dAB * dCA, db = dBC * dAB, dc = dCA * dBC;
            vr = (ca / da + cb / db) + cc / dc;
            vi = -((sa / da + sb / db) + sc / dc);
        }
        atomicAdd(&pg[2 * p + 0], (float)area * (float)vr);
        atomicAdd(&pg[2 * p + 1], (float)area * (float)vi);
    }
}

// ---- Kernel C: combine face-half partials, scale by 2/meshar, mirror-write ----
__global__ __launch_bounds__(256) void combine(
        const double* __restrict__ ws, float* __restrict__ out, int interleaved) {
    const int p = blockIdx.x * 256 + threadIdx.x;  // [0, kHalf)
    const float* psum = (const float*)ws;
    const float meshar = ((psum[0] + psum[1]) + psum[2]) + psum[3];
    const float inv2 = 2.0f / meshar;
    const float2* pg = (const float2*)(ws + kGridOffD);
    const float2 a = pg[p];
    const float2 b = pg[kHalf + p];
    const float R = (a.x + b.x) * inv2;
    const float I = (a.y + b.y) * inv2;
    const int q = kNpts - 1 - p;
    if (interleaved) {
        ((float2*)out)[p] = make_float2(R, I);
        ((float2*)out)[q] = make_float2(R, -I);
    } else {
        out[p] = R;
        out[q] = R;
    }
}

extern "C" void kernel_launch(void* const* d_in, const int* in_sizes, int n_in,
                              void* d_out, int out_size, void* d_ws, size_t ws_size,
                              hipStream_t stream) {
    const float* verts = (const float*)d_in[0];
    const float* box   = (const float*)d_in[1];
    const float* xi0v  = (const float*)d_in[2];
    const float* xi1v  = (const float*)d_in[3];
    const float* xi2v  = (const float*)d_in[4];
    const int*   faces = (const int*)d_in[5];
    double* ws = (double*)d_ws;

    const int interleaved = (out_size == 2 * kNpts) ? 1 : 0;

    // slow-pair list capacity from whatever workspace remains past the grids
    const size_t listByteOff = (size_t)kSlowListD * 8;
    int cap = 0;
    if (ws_size > listByteOff + 4) {
        size_t c = (ws_size - listByteOff) / 4;
        if (c > (size_t)(1 << 22)) c = (size_t)(1 << 22);
        cap = (int)c;
    }

    hipLaunchKernelGGL(face_prep, dim3(kNF / 256), dim3(256), 0, stream,
                       verts, box, faces, ws);
    hipLaunchKernelGGL(fourier_main, dim3((kHalf / 64) * kFaceHalves),
                       dim3(kWaves * 64), 0, stream, ws, xi0v, xi1v, xi2v, cap);
    hipLaunchKernelGGL(fourier_fix, dim3(32), dim3(256), 0, stream,
                       ws, xi0v, xi1v, xi2v, cap);
    hipLaunchKernelGGL(combine, dim3(kHalf / 256), dim3(256), 0, stream,
                       ws, (float*)d_out, interleaved);
}